// Round 2
// baseline (26895.200 us; speedup 1.0000x reference)
//
#include <hip/hip_runtime.h>
#include <math.h>

#define BATCHN 32
#define SEQT   2048
#define NMELS  80
#define HIDN   512
#define NCLSN  64
#define BTROWS (BATCHN*SEQT)   // 65536

__device__ inline float wave_sum(float v) {
  #pragma unroll
  for (int o = 32; o > 0; o >>= 1) v += __shfl_xor(v, o, 64);
  return v;
}
__device__ inline float ftanh(float x) {
  float ax = fabsf(x);
  float e = __expf(2.0f*ax);
  float t = 1.0f - 2.0f/(e + 1.0f);
  return copysignf(t, x);
}
__device__ inline unsigned pack_bf16(float a, float b) {
  union { float f; unsigned u; } ua, ub; ua.f = a; ub.f = b;
  unsigned lo = (ua.u + 0x7fffu + ((ua.u >> 16) & 1u)) >> 16;
  unsigned hi = (ub.u + 0x7fffu + ((ub.u >> 16) & 1u)) & 0xffff0000u;
  return (lo & 0xffffu) | hi;
}
__device__ inline float bf_lo(unsigned p) { union { unsigned u; float f; } c; c.u = p << 16; return c.f; }
__device__ inline float bf_hi(unsigned p) { union { unsigned u; float f; } c; c.u = p & 0xffff0000u; return c.f; }

// ---------------- row L2-norm: xs[m] = max(||X[m,:]||, 1e-6) ----------------
__global__ __launch_bounds__(256) void rownorm_kernel(
    const float* __restrict__ X, float* __restrict__ xs, int M, int K)
{
  int wave = threadIdx.x >> 6, lane = threadIdx.x & 63;
  int m = blockIdx.x*4 + wave;
  if (m >= M) return;
  const float* row = X + (size_t)m*K;
  float acc = 0.f;
  for (int k = lane; k < K; k += 64) { float v = row[k]; acc += v*v; }
  acc = wave_sum(acc);
  if (lane == 0) xs[m] = fmaxf(sqrtf(acc), 1e-6f);
}

// ---------------- out init: out[b,t,c] = head_b[c] ----------------
__global__ __launch_bounds__(256) void initout_kernel(
    float* __restrict__ out, const float* __restrict__ head_b)
{
  int i4 = blockIdx.x*256 + threadIdx.x;         // float4 index
  float4 v = ((const float4*)head_b)[i4 & 15];   // 64 floats = 16 float4, repeats
  ((float4*)out)[i4] = v;
}

// ---------------- fused cell-1 recurrence + head ----------------
// 256 WGs = 32 batches x 8 slices of 64 rows. ONE spin barrier per step.
// Pre-barrier (per WG): be0 slice (B0 slice, LDS), column-slice partials of
//   g_pre = C1 @ h  and  be1_pre = B1 @ be0  (h slice is WG-local!), ||be0_own||^2.
// Post-barrier: sum 8 partials -> g, be1; error, surprise (redundant per WG);
//   err_eff = W1[slice,:] @ error (row slice, regs); h update; head atomicAdd.
__global__ __launch_bounds__(256, 1) void recur_kernel(
    const float* __restrict__ feats,
    const float* __restrict__ B0,
    const float* __restrict__ C1, const float* __restrict__ B1,
    const float* __restrict__ W1,
    const float* __restrict__ ltc,
    const float* __restrict__ tau0p, const float* __restrict__ gammap,
    const float* __restrict__ head_w,
    const float* __restrict__ xs0v,
    float* __restrict__ out,
    float* __restrict__ PG, float* __restrict__ PB,
    float* __restrict__ BE, float* __restrict__ PS,
    unsigned int* __restrict__ cnt)
{
  const int wg = blockIdx.x;
  const int x = wg & 7, s = (wg >> 3) & 7, qq = wg >> 6;
  const int b = x*4 + qq;        // 8 slices of batch b share blockIdx%8 (XCD heuristic)
  const int row0 = s*64;
  const int tid = threadIdx.x;
  const int r = tid >> 2, kc = tid & 3;
  const int wid = tid >> 6, lane = tid & 63;

  __shared__ float b0_s[64*84];    // B0 slice, padded stride 84
  __shared__ float whh_s[64*68];   // head_w[c][row0+j]      (h half), stride 68
  __shared__ float whb_s[64*68];   // head_w[c][512+row0+j]  (be1 half)
  __shared__ float er_s[512];
  __shared__ float ft_s[80];
  __shared__ float h_s[64];
  __shared__ float bo_s[64];
  __shared__ float bv_s[64];
  __shared__ float a0_s[64];
  __shared__ float red_s[4], red2_s[4];

  // ---- static weights into registers ----
  float c1c[128];    // C1 column-slice: c1c[j*64+k] = C1[tid+j*256][row0+k]
  unsigned b1p[64];  // B1 column-slice, bf16-packed pairs
  float w1r[128];    // W1 row-slice, bank-staggered float4 order
  #pragma unroll
  for (int j = 0; j < 2; j++) {
    const float* src = C1 + (size_t)(tid + j*256)*512 + row0;
    #pragma unroll
    for (int k4 = 0; k4 < 16; k4++) {
      float4 v = *(const float4*)(src + 4*k4);
      c1c[j*64+4*k4]=v.x; c1c[j*64+4*k4+1]=v.y; c1c[j*64+4*k4+2]=v.z; c1c[j*64+4*k4+3]=v.w;
    }
  }
  #pragma unroll
  for (int j = 0; j < 2; j++) {
    const float* src = B1 + (size_t)(tid + j*256)*512 + row0;
    #pragma unroll
    for (int k4 = 0; k4 < 16; k4++) {
      float4 v = *(const float4*)(src + 4*k4);
      b1p[j*32+2*k4]   = pack_bf16(v.x, v.y);
      b1p[j*32+2*k4+1] = pack_bf16(v.z, v.w);
    }
  }
  {
    const float* src = W1 + (size_t)(row0 + r)*512;
    #pragma unroll
    for (int j4 = 0; j4 < 32; j4++) {
      const int f = kc*32 + ((j4 + kc) & 31);
      float4 v = *(const float4*)(src + 4*f);
      w1r[4*j4]=v.x; w1r[4*j4+1]=v.y; w1r[4*j4+2]=v.z; w1r[4*j4+3]=v.w;
    }
  }
  for (int i = tid; i < 5120; i += 256) {
    int rr = i/80, kk = i - rr*80;
    b0_s[rr*84 + kk] = B0[(size_t)(row0+rr)*80 + kk];
  }
  for (int i = tid; i < 4096; i += 256) {
    int c = i >> 6, j = i & 63;
    whh_s[c*68+j] = head_w[(size_t)c*1024 + row0 + j];
    whb_s[c*68+j] = head_w[(size_t)c*1024 + 512 + row0 + j];
  }
  if (tid < 64) {
    float xv = ltc[row0 + tid];
    float spl = (xv > 20.f) ? xv : log1pf(__expf(xv));
    a0_s[tid] = 0.1f / (1.0f + spl);
    h_s[tid] = 0.f;
  }
  const float tau0v = *tau0p, gmv = *gammap;
  unsigned int* cb = cnt + b*32;    // 128B-padded counter per batch
  __syncthreads();

  for (int t = 0; t < SEQT; ++t) {
    const int par = t & 1;
    float* PGw = PG + (((size_t)par*BATCHN + b)*8 + s)*512;
    float* PBw = PB + (((size_t)par*BATCHN + b)*8 + s)*512;
    float* BEb = BE + ((size_t)par*BATCHN + b)*512;
    float* PSb = PS + ((size_t)par*BATCHN + b)*8;
    const size_t bt = (size_t)b*SEQT + t;

    if (tid < 80) ft_s[tid] = feats[bt*80 + tid];
    const float rxs0 = 1.0f / xs0v[bt];
    __syncthreads();

    // ---- be0 slice: 4 threads/row x 20 k ----
    float a = 0.f;
    #pragma unroll
    for (int j4 = 0; j4 < 5; j4++) {
      float4 bw = *(const float4*)(b0_s + r*84 + kc*20 + 4*j4);
      float4 fv = *(const float4*)(ft_s + kc*20 + 4*j4);
      a += bw.x*fv.x + bw.y*fv.y + bw.z*fv.z + bw.w*fv.w;
    }
    a += __shfl_xor(a, 1, 64); a += __shfl_xor(a, 2, 64);
    const float be0v = a * rxs0;                 // all 4 lanes of row r hold it
    if (kc == 0) {
      bo_s[r] = be0v;
      __hip_atomic_store(&BEb[row0 + r], be0v, __ATOMIC_RELAXED, __HIP_MEMORY_SCOPE_AGENT);
    }
    float sq = 0.25f*be0v*be0v;                  // each row counted 4x -> 0.25
    sq = wave_sum(sq);
    if (lane == 0) red_s[wid] = sq;
    __syncthreads();                              // bo_s, red_s ready

    // ---- column-slice partials: g_pre and be1_pre ----
    float pg0=0.f, pg1=0.f, pb0=0.f, pb1=0.f;
    #pragma unroll
    for (int k4 = 0; k4 < 16; k4++) {
      float4 hv = *(const float4*)(h_s + 4*k4);
      float4 ov = *(const float4*)(bo_s + 4*k4);
      pg0 += c1c[4*k4]*hv.x + c1c[4*k4+1]*hv.y + c1c[4*k4+2]*hv.z + c1c[4*k4+3]*hv.w;
      pg1 += c1c[64+4*k4]*hv.x + c1c[64+4*k4+1]*hv.y + c1c[64+4*k4+2]*hv.z + c1c[64+4*k4+3]*hv.w;
      unsigned p0 = b1p[2*k4], p1 = b1p[2*k4+1];
      unsigned q0 = b1p[32+2*k4], q1 = b1p[32+2*k4+1];
      pb0 += bf_lo(p0)*ov.x + bf_hi(p0)*ov.y + bf_lo(p1)*ov.z + bf_hi(p1)*ov.w;
      pb1 += bf_lo(q0)*ov.x + bf_hi(q0)*ov.y + bf_lo(q1)*ov.z + bf_hi(q1)*ov.w;
    }
    __hip_atomic_store(&PGw[tid],     pg0, __ATOMIC_RELAXED, __HIP_MEMORY_SCOPE_AGENT);
    __hip_atomic_store(&PGw[tid+256], pg1, __ATOMIC_RELAXED, __HIP_MEMORY_SCOPE_AGENT);
    __hip_atomic_store(&PBw[tid],     pb0, __ATOMIC_RELAXED, __HIP_MEMORY_SCOPE_AGENT);
    __hip_atomic_store(&PBw[tid+256], pb1, __ATOMIC_RELAXED, __HIP_MEMORY_SCOPE_AGENT);
    __syncthreads();   // compiler drains vmcnt before s_barrier -> stores visible

    if (tid == 0) {
      float ps = red_s[0]+red_s[1]+red_s[2]+red_s[3];
      __hip_atomic_store(&PSb[s], ps, __ATOMIC_RELAXED, __HIP_MEMORY_SCOPE_AGENT);
      __hip_atomic_fetch_add(cb, 1u, __ATOMIC_RELEASE, __HIP_MEMORY_SCOPE_AGENT);
      const unsigned tgt = 8u*(unsigned)(t+1);
      while (__hip_atomic_load(cb, __ATOMIC_ACQUIRE, __HIP_MEMORY_SCOPE_AGENT) < tgt)
        __builtin_amdgcn_s_sleep(1);
    }
    __syncthreads();

    // ---- post-barrier: gather ----
    const float* PGr = PG + ((size_t)par*BATCHN + b)*8*512;
    const float* PBr = PB + ((size_t)par*BATCHN + b)*8*512;
    float xsq = 0.f;
    #pragma unroll
    for (int s2 = 0; s2 < 8; s2++)
      xsq += __hip_atomic_load(&PSb[s2], __ATOMIC_RELAXED, __HIP_MEMORY_SCOPE_AGENT);
    const float xs1 = fmaxf(sqrtf(xsq), 1e-6f);
    const float rxs1 = 1.0f / xs1;

    float gp0=0.f, gp1=0.f;
    #pragma unroll
    for (int s2 = 0; s2 < 8; s2++) {
      gp0 += __hip_atomic_load(&PGr[s2*512 + tid],     __ATOMIC_RELAXED, __HIP_MEMORY_SCOPE_AGENT);
      gp1 += __hip_atomic_load(&PGr[s2*512 + tid+256], __ATOMIC_RELAXED, __HIP_MEMORY_SCOPE_AGENT);
    }
    const float bea = __hip_atomic_load(&BEb[tid],     __ATOMIC_RELAXED, __HIP_MEMORY_SCOPE_AGENT);
    const float beb = __hip_atomic_load(&BEb[tid+256], __ATOMIC_RELAXED, __HIP_MEMORY_SCOPE_AGENT);
    const float e0 = bea - xs1*ftanh(gp0);
    const float e1 = beb - xs1*ftanh(gp1);
    er_s[tid] = e0; er_s[tid+256] = e1;
    float es = wave_sum(e0*e0 + e1*e1);
    if (lane == 0) red2_s[wid] = es;

    float pbv = __hip_atomic_load(&PBr[(2*kc)*512   + row0 + r], __ATOMIC_RELAXED, __HIP_MEMORY_SCOPE_AGENT)
              + __hip_atomic_load(&PBr[(2*kc+1)*512 + row0 + r], __ATOMIC_RELAXED, __HIP_MEMORY_SCOPE_AGENT);
    pbv += __shfl_xor(pbv, 1, 64); pbv += __shfl_xor(pbv, 2, 64);
    const float be1v = pbv * rxs1;               // x_norm clip is a no-op: |be0_k| <= ||be0||
    if (kc == 0) bv_s[r] = be1v;
    __syncthreads();                              // er_s, red2_s, bv_s ready

    const float rel = fminf(sqrtf(red2_s[0]+red2_s[1]+red2_s[2]+red2_s[3]) * rxs1, 4.0f);
    const float sp = 1.0f/(1.0f + __expf(-(rel - tau0v)/gmv));

    // ---- err_eff row-slice matvec (bank-staggered er_s reads) ----
    float ee = 0.f;
    #pragma unroll
    for (int j4 = 0; j4 < 32; j4++) {
      const int f = kc*32 + ((j4 + kc) & 31);
      float4 ev = *(const float4*)(er_s + 4*f);
      ee += w1r[4*j4]*ev.x + w1r[4*j4+1]*ev.y + w1r[4*j4+2]*ev.z + w1r[4*j4+3]*ev.w;
    }
    ee += __shfl_xor(ee, 1, 64); ee += __shfl_xor(ee, 2, 64);

    const float hold = h_s[r];
    const float ih = 0.2f*hold + 0.6f*be1v + 0.2f*sp*ee;
    const float th = ftanh(ih);
    const float hn = hold + a0_s[r]*(1.0f + sp)*(th - hold);
    if (kc == 0) h_s[r] = hn;
    __syncthreads();                              // h_s new ready

    // ---- head: out[b,t,c] += sum_{j in slice} h[j]*whh[c,j] + be1[j]*whb[c,j] ----
    {
      const int c = r; const int j0 = kc*16;
      float hacc = 0.f;
      #pragma unroll
      for (int j4 = 0; j4 < 4; j4++) {
        float4 hv4 = *(const float4*)(h_s  + j0 + 4*j4);
        float4 bv4 = *(const float4*)(bv_s + j0 + 4*j4);
        float4 wh  = *(const float4*)(whh_s + c*68 + j0 + 4*j4);
        float4 wb  = *(const float4*)(whb_s + c*68 + j0 + 4*j4);
        hacc += hv4.x*wh.x + hv4.y*wh.y + hv4.z*wh.z + hv4.w*wh.w
              + bv4.x*wb.x + bv4.y*wb.y + bv4.z*wb.z + bv4.w*wb.w;
      }
      hacc += __shfl_xor(hacc, 1, 64); hacc += __shfl_xor(hacc, 2, 64);
      if (kc == 0) atomicAdd(&out[bt*64 + c], hacc);
    }
    // no end-of-loop sync needed: next writes to shared state are separated by
    // the ft/bo syncs (WG-local) or the next spin barrier (cross-WG, dbl-buffered)
  }
}

extern "C" void kernel_launch(void* const* d_in, const int* in_sizes, int n_in,
                              void* d_out, int out_size, void* d_ws, size_t ws_size,
                              hipStream_t stream)
{
  (void)in_sizes; (void)n_in; (void)out_size;
  const float* feats  = (const float*)d_in[0];
  const float* B0     = (const float*)d_in[2];
  const float* C1     = (const float*)d_in[7];
  const float* B1     = (const float*)d_in[8];
  const float* W1     = (const float*)d_in[9];
  const float* tau0_1 = (const float*)d_in[10];
  const float* gamma1 = (const float*)d_in[11];
  const float* ltc1   = (const float*)d_in[12];
  const float* head_w = (const float*)d_in[13];
  const float* head_b = (const float*)d_in[14];
  float* out = (float*)d_out;

  // ws layout (fp32 unless noted): PG[2][32][8][512] | PB[2][32][8][512] |
  //   BE[2][32][512] | PS[2][32][8] | xs0[65536] | cnt[32*32 u32]   (~2.8 MB)
  float* PG  = (float*)d_ws;
  float* PB  = PG + (size_t)2*BATCHN*8*HIDN;
  float* BE  = PB + (size_t)2*BATCHN*8*HIDN;
  float* PS  = BE + (size_t)2*BATCHN*HIDN;
  float* xs0 = PS + (size_t)2*BATCHN*8;
  unsigned int* cnt = (unsigned int*)(xs0 + BTROWS);
  size_t needed = (size_t)((char*)(cnt + BATCHN*32) - (char*)d_ws);
  if (ws_size < needed) return;   // ~2.8 MB — comfortably small

  rownorm_kernel<<<BTROWS/4, 256, 0, stream>>>(feats, xs0, BTROWS, NMELS);
  initout_kernel<<<(BTROWS*NCLSN/4)/256, 256, 0, stream>>>(out, head_b);
  hipMemsetAsync(cnt, 0, BATCHN*32*sizeof(unsigned int), stream);

  void* args[] = { (void*)&feats, (void*)&B0, (void*)&C1, (void*)&B1, (void*)&W1,
                   (void*)&ltc1, (void*)&tau0_1, (void*)&gamma1, (void*)&head_w,
                   (void*)&xs0, (void*)&out,
                   (void*)&PG, (void*)&PB, (void*)&BE, (void*)&PS, (void*)&cnt };
  hipError_t e = hipLaunchCooperativeKernel((void*)recur_kernel, dim3(256), dim3(256),
                                            args, 0, stream);
  if (e != hipSuccess) {
    recur_kernel<<<256, 256, 0, stream>>>(feats, B0, C1, B1, W1, ltc1, tau0_1, gamma1,
                                          head_w, xs0, out, PG, PB, BE, PS, cnt);
  }
}